// Round 1
// baseline (8661.819 us; speedup 1.0000x reference)
//
#include <hip/hip_runtime.h>

// GraphSAGE 3-layer, N=100000 nodes, E=1600000 edges, 128->128->16, f32.
// out = sage2( relu(bn1( sage1( relu(bn0( sage0(x) )) ) )) )
// sage(h) = (segment_mean(h[src], dst)) @ Wn + b + h @ Ws

constexpr int N  = 100000;
constexpr int E  = 1600000;
constexpr int F  = 128;
constexpr int FO = 16;

// ---------------- edge-count kernel (in-degree as float) ----------------
__global__ void count_k(const int* __restrict__ dst, float* __restrict__ cnt) {
  int i = blockIdx.x * blockDim.x + threadIdx.x;
  int stride = gridDim.x * blockDim.x;
  for (; i < E; i += stride) atomicAdd(&cnt[dst[i]], 1.0f);
}

// ---------------- scatter-add: s[dst] += h[src], 128 ch ----------------
// one thread = one float4 chunk of one edge; 32 consecutive threads share an edge
__global__ void scatter_k(const int* __restrict__ src, const int* __restrict__ dst,
                          const float* __restrict__ h, float* __restrict__ s) {
  const int total = E * 32;  // 51.2M, fits int
  int i = blockIdx.x * blockDim.x + threadIdx.x;
  int stride = gridDim.x * blockDim.x;
  for (; i < total; i += stride) {
    int e = i >> 5;
    int c = (i & 31) << 2;
    int sv = src[e], dv = dst[e];
    float4 v = *reinterpret_cast<const float4*>(h + (size_t)sv * F + c);
    float* p = s + (size_t)dv * F + c;
    atomicAdd(p + 0, v.x);
    atomicAdd(p + 1, v.y);
    atomicAdd(p + 2, v.z);
    atomicAdd(p + 3, v.w);
  }
}

// ------------- fused hidden layer: h_out = relu(bn((s/cnt)@Wn + b + h@Ws)) -------------
// block = 256 threads handles 32 rows x 128 cols; thread = (half,c), 16 rows each
__global__ __launch_bounds__(256) void fused_hidden_k(
    const float* __restrict__ s, const float* __restrict__ cnt,
    const float* __restrict__ h_in,
    const float* __restrict__ Wn, const float* __restrict__ b,
    const float* __restrict__ Ws,
    const float* __restrict__ g, const float* __restrict__ be,
    const float* __restrict__ rm, const float* __restrict__ rv,
    float* __restrict__ h_out) {
  __shared__ float aggL[32][F];
  __shared__ float hL[32][F];
  const int tid = threadIdx.x;
  const int row0 = blockIdx.x * 32;

  // cooperative load: 32 rows * 128 = 1024 float4 per array, 4 per thread
  const float4* sg = reinterpret_cast<const float4*>(s + (size_t)row0 * F);
  const float4* hg = reinterpret_cast<const float4*>(h_in + (size_t)row0 * F);
  float4* aggv = reinterpret_cast<float4*>(&aggL[0][0]);
  float4* hv   = reinterpret_cast<float4*>(&hL[0][0]);
#pragma unroll
  for (int j = 0; j < 4; ++j) {
    int f = tid + j * 256;          // float4 index within tile
    int r = f >> 5;                 // row within tile (f*4/128)
    float inv = 1.0f / fmaxf(cnt[row0 + r], 1.0f);
    float4 sv4 = sg[f];
    float4 hv4 = hg[f];
    aggv[f] = make_float4(sv4.x * inv, sv4.y * inv, sv4.z * inv, sv4.w * inv);
    hv[f] = hv4;
  }
  __syncthreads();

  const int c = tid & 127;
  const int half = tid >> 7;  // 0 or 1 -> rows [0,16) or [16,32)
  float acc[16];
#pragma unroll
  for (int r = 0; r < 16; ++r) acc[r] = 0.0f;

  for (int k0 = 0; k0 < F; k0 += 4) {
    float wn0 = Wn[(k0 + 0) * F + c];
    float wn1 = Wn[(k0 + 1) * F + c];
    float wn2 = Wn[(k0 + 2) * F + c];
    float wn3 = Wn[(k0 + 3) * F + c];
    float ws0 = Ws[(k0 + 0) * F + c];
    float ws1 = Ws[(k0 + 1) * F + c];
    float ws2 = Ws[(k0 + 2) * F + c];
    float ws3 = Ws[(k0 + 3) * F + c];
#pragma unroll
    for (int r = 0; r < 16; ++r) {
      int rr = half * 16 + r;
      float4 a  = *reinterpret_cast<const float4*>(&aggL[rr][k0]);
      float4 h4 = *reinterpret_cast<const float4*>(&hL[rr][k0]);
      acc[r] += a.x * wn0 + a.y * wn1 + a.z * wn2 + a.w * wn3
              + h4.x * ws0 + h4.y * ws1 + h4.z * ws2 + h4.w * ws3;
    }
  }

  // epilogue: bias + BN(eval) + relu
  float bias  = b[c];
  float scale = rsqrtf(rv[c] + 1e-5f) * g[c];
  float rmc = rm[c], bec = be[c];
#pragma unroll
  for (int r = 0; r < 16; ++r) {
    int rr = half * 16 + r;
    float o = (acc[r] + bias - rmc) * scale + bec;
    h_out[(size_t)(row0 + rr) * F + c] = fmaxf(o, 0.0f);
  }
}

// ------------- output layer: out = (s/cnt)@Wn2 + b2 + h@Ws2  (128 -> 16) -------------
// block = 256 threads handles 16 rows x 16 cols; one output per thread
__global__ __launch_bounds__(256) void out_k(
    const float* __restrict__ s, const float* __restrict__ cnt,
    const float* __restrict__ h_in,
    const float* __restrict__ Wn, const float* __restrict__ b,
    const float* __restrict__ Ws,
    float* __restrict__ out) {
  __shared__ float aggL[16][F];
  __shared__ float hL[16][F];
  const int tid = threadIdx.x;
  const int row0 = blockIdx.x * 16;

  const float4* sg = reinterpret_cast<const float4*>(s + (size_t)row0 * F);
  const float4* hg = reinterpret_cast<const float4*>(h_in + (size_t)row0 * F);
  float4* aggv = reinterpret_cast<float4*>(&aggL[0][0]);
  float4* hv   = reinterpret_cast<float4*>(&hL[0][0]);
#pragma unroll
  for (int j = 0; j < 2; ++j) {
    int f = tid + j * 256;   // float4 index 0..511
    int r = f >> 5;
    float inv = 1.0f / fmaxf(cnt[row0 + r], 1.0f);
    float4 sv4 = sg[f];
    float4 hv4 = hg[f];
    aggv[f] = make_float4(sv4.x * inv, sv4.y * inv, sv4.z * inv, sv4.w * inv);
    hv[f] = hv4;
  }
  __syncthreads();

  const int c = tid & 15;
  const int r = tid >> 4;
  float acc = 0.0f;
  for (int k0 = 0; k0 < F; k0 += 4) {
    float4 a  = *reinterpret_cast<const float4*>(&aggL[r][k0]);
    float4 h4 = *reinterpret_cast<const float4*>(&hL[r][k0]);
    acc += a.x * Wn[(k0 + 0) * FO + c] + a.y * Wn[(k0 + 1) * FO + c]
         + a.z * Wn[(k0 + 2) * FO + c] + a.w * Wn[(k0 + 3) * FO + c]
         + h4.x * Ws[(k0 + 0) * FO + c] + h4.y * Ws[(k0 + 1) * FO + c]
         + h4.z * Ws[(k0 + 2) * FO + c] + h4.w * Ws[(k0 + 3) * FO + c];
  }
  out[(size_t)(row0 + r) * FO + c] = acc + b[c];
}

extern "C" void kernel_launch(void* const* d_in, const int* in_sizes, int n_in,
                              void* d_out, int out_size, void* d_ws, size_t ws_size,
                              hipStream_t stream) {
  const float* x   = (const float*)d_in[0];
  const int*   ei  = (const int*)d_in[1];
  const float* Wn0 = (const float*)d_in[2];
  const float* b0  = (const float*)d_in[3];
  const float* Ws0 = (const float*)d_in[4];
  const float* Wn1 = (const float*)d_in[5];
  const float* b1  = (const float*)d_in[6];
  const float* Ws1 = (const float*)d_in[7];
  const float* Wn2 = (const float*)d_in[8];
  const float* b2  = (const float*)d_in[9];
  const float* Ws2 = (const float*)d_in[10];
  const float* g0  = (const float*)d_in[11];
  const float* be0 = (const float*)d_in[12];
  const float* rm0 = (const float*)d_in[13];
  const float* rv0 = (const float*)d_in[14];
  const float* g1  = (const float*)d_in[15];
  const float* be1 = (const float*)d_in[16];
  const float* rm1 = (const float*)d_in[17];
  const float* rv1 = (const float*)d_in[18];

  const int* src = ei;       // edge_index[0]
  const int* dst = ei + E;   // edge_index[1]

  // workspace layout (floats): cnt[102400 pad] | s[N*F] | h0[N*F] | h1[N*F]  ~154 MB
  float* ws  = (float*)d_ws;
  float* cnt = ws;
  float* s   = ws + 102400;
  float* h0  = s + (size_t)N * F;
  float* h1  = h0 + (size_t)N * F;

  // ---- layer 0 ----
  hipMemsetAsync(cnt, 0, N * sizeof(float), stream);
  hipMemsetAsync(s, 0, (size_t)N * F * sizeof(float), stream);
  count_k<<<2048, 256, 0, stream>>>(dst, cnt);
  scatter_k<<<2048, 256, 0, stream>>>(src, dst, x, s);
  fused_hidden_k<<<N / 32, 256, 0, stream>>>(s, cnt, x, Wn0, b0, Ws0,
                                             g0, be0, rm0, rv0, h0);

  // ---- layer 1 ----
  hipMemsetAsync(s, 0, (size_t)N * F * sizeof(float), stream);
  scatter_k<<<2048, 256, 0, stream>>>(src, dst, h0, s);
  fused_hidden_k<<<N / 32, 256, 0, stream>>>(s, cnt, h0, Wn1, b1, Ws1,
                                             g1, be1, rm1, rv1, h1);

  // ---- layer 2 (output) ----
  hipMemsetAsync(s, 0, (size_t)N * F * sizeof(float), stream);
  scatter_k<<<2048, 256, 0, stream>>>(src, dst, h1, s);
  out_k<<<N / 16, 256, 0, stream>>>(s, cnt, h1, Wn2, b2, Ws2, (float*)d_out);
}

// Round 2
// 946.998 us; speedup vs baseline: 9.1466x; 9.1466x over previous
//
#include <hip/hip_runtime.h>

// GraphSAGE 3-layer, N=100000 nodes, E=1600000 edges, 128->128->16, f32.
// R2: replace scatter-atomic aggregation (205M float atomics/layer, 93% of time)
// with a build-once bucket table + gather-sum per node. Graph identical across
// layers -> build once, aggregate 3x with zero float atomics.

constexpr int N   = 100000;
constexpr int E   = 1600000;
constexpr int F   = 128;
constexpr int FO  = 16;
constexpr int CAP = 64;   // max in-degree; Poisson(16), P(deg>64) ~ 1e-18/node

// ---------------- bucket fill: slots[dst][k] = src, degc[dst] = in-degree ----
__global__ void fill_k(const int* __restrict__ src, const int* __restrict__ dst,
                       int* __restrict__ degc, int* __restrict__ slots) {
  int i = blockIdx.x * blockDim.x + threadIdx.x;
  int stride = gridDim.x * blockDim.x;
  for (; i < E; i += stride) {
    int d = dst[i];
    int pos = atomicAdd(&degc[d], 1);
    if (pos < CAP) slots[(size_t)d * CAP + pos] = src[i];
  }
}

// ---------------- gather-mean: agg[n][c] = mean_{e in N(n)} h[src_e][c] ------
// block = 256 threads = 2 nodes x 128 channels
__global__ __launch_bounds__(256) void agg_k(const int* __restrict__ degc,
                                             const int* __restrict__ slots,
                                             const float* __restrict__ h,
                                             float* __restrict__ agg) {
  int node = blockIdx.x * 2 + (threadIdx.x >> 7);
  int c = threadIdx.x & 127;
  int deg = degc[node];
  if (deg > CAP) deg = CAP;
  const int* sl = slots + (size_t)node * CAP;
  float s0 = 0.f, s1 = 0.f, s2 = 0.f, s3 = 0.f;
  int e = 0;
  for (; e + 4 <= deg; e += 4) {           // 4 partial sums -> 4 loads in flight
    int a0 = sl[e], a1 = sl[e + 1], a2 = sl[e + 2], a3 = sl[e + 3];
    s0 += h[(size_t)a0 * F + c];
    s1 += h[(size_t)a1 * F + c];
    s2 += h[(size_t)a2 * F + c];
    s3 += h[(size_t)a3 * F + c];
  }
  for (; e < deg; ++e) s0 += h[(size_t)sl[e] * F + c];
  float sum = (s0 + s1) + (s2 + s3);
  agg[(size_t)node * F + c] = sum / fmaxf((float)deg, 1.0f);
}

// ------------- fused hidden layer: h_out = relu(bn(agg@Wn + b + h@Ws)) -------
// block = 256 threads handles 32 rows x 128 cols; thread = (half,c), 16 rows each
// NOTE: safe for h_out == h_in (all h_in reads happen before the final writes,
// and each block only touches its own 32 rows).
__global__ __launch_bounds__(256) void fused_hidden_k(
    const float* __restrict__ agg_in, const float* __restrict__ h_in,
    const float* __restrict__ Wn, const float* __restrict__ b,
    const float* __restrict__ Ws,
    const float* __restrict__ g, const float* __restrict__ be,
    const float* __restrict__ rm, const float* __restrict__ rv,
    float* __restrict__ h_out) {
  __shared__ float aggL[32][F];
  __shared__ float hL[32][F];
  const int tid = threadIdx.x;
  const int row0 = blockIdx.x * 32;

  const float4* ag = reinterpret_cast<const float4*>(agg_in + (size_t)row0 * F);
  const float4* hg = reinterpret_cast<const float4*>(h_in + (size_t)row0 * F);
  float4* aggv = reinterpret_cast<float4*>(&aggL[0][0]);
  float4* hv   = reinterpret_cast<float4*>(&hL[0][0]);
#pragma unroll
  for (int j = 0; j < 4; ++j) {
    int f = tid + j * 256;
    aggv[f] = ag[f];
    hv[f] = hg[f];
  }
  __syncthreads();

  const int c = tid & 127;
  const int half = tid >> 7;
  float acc[16];
#pragma unroll
  for (int r = 0; r < 16; ++r) acc[r] = 0.0f;

  for (int k0 = 0; k0 < F; k0 += 4) {
    float wn0 = Wn[(k0 + 0) * F + c];
    float wn1 = Wn[(k0 + 1) * F + c];
    float wn2 = Wn[(k0 + 2) * F + c];
    float wn3 = Wn[(k0 + 3) * F + c];
    float ws0 = Ws[(k0 + 0) * F + c];
    float ws1 = Ws[(k0 + 1) * F + c];
    float ws2 = Ws[(k0 + 2) * F + c];
    float ws3 = Ws[(k0 + 3) * F + c];
#pragma unroll
    for (int r = 0; r < 16; ++r) {
      int rr = half * 16 + r;
      float4 a  = *reinterpret_cast<const float4*>(&aggL[rr][k0]);
      float4 h4 = *reinterpret_cast<const float4*>(&hL[rr][k0]);
      acc[r] += a.x * wn0 + a.y * wn1 + a.z * wn2 + a.w * wn3
              + h4.x * ws0 + h4.y * ws1 + h4.z * ws2 + h4.w * ws3;
    }
  }

  float bias  = b[c];
  float scale = rsqrtf(rv[c] + 1e-5f) * g[c];
  float rmc = rm[c], bec = be[c];
#pragma unroll
  for (int r = 0; r < 16; ++r) {
    int rr = half * 16 + r;
    float o = (acc[r] + bias - rmc) * scale + bec;
    h_out[(size_t)(row0 + rr) * F + c] = fmaxf(o, 0.0f);
  }
}

// ------------- output layer: out = agg@Wn2 + b2 + h@Ws2  (128 -> 16) ---------
__global__ __launch_bounds__(256) void out_k(
    const float* __restrict__ agg_in, const float* __restrict__ h_in,
    const float* __restrict__ Wn, const float* __restrict__ b,
    const float* __restrict__ Ws,
    float* __restrict__ out) {
  __shared__ float aggL[16][F];
  __shared__ float hL[16][F];
  const int tid = threadIdx.x;
  const int row0 = blockIdx.x * 16;

  const float4* ag = reinterpret_cast<const float4*>(agg_in + (size_t)row0 * F);
  const float4* hg = reinterpret_cast<const float4*>(h_in + (size_t)row0 * F);
  float4* aggv = reinterpret_cast<float4*>(&aggL[0][0]);
  float4* hv   = reinterpret_cast<float4*>(&hL[0][0]);
#pragma unroll
  for (int j = 0; j < 2; ++j) {
    int f = tid + j * 256;
    aggv[f] = ag[f];
    hv[f] = hg[f];
  }
  __syncthreads();

  const int c = tid & 15;
  const int r = tid >> 4;
  float acc = 0.0f;
  for (int k0 = 0; k0 < F; k0 += 4) {
    float4 a  = *reinterpret_cast<const float4*>(&aggL[r][k0]);
    float4 h4 = *reinterpret_cast<const float4*>(&hL[r][k0]);
    acc += a.x * Wn[(k0 + 0) * FO + c] + a.y * Wn[(k0 + 1) * FO + c]
         + a.z * Wn[(k0 + 2) * FO + c] + a.w * Wn[(k0 + 3) * FO + c]
         + h4.x * Ws[(k0 + 0) * FO + c] + h4.y * Ws[(k0 + 1) * FO + c]
         + h4.z * Ws[(k0 + 2) * FO + c] + h4.w * Ws[(k0 + 3) * FO + c];
  }
  out[(size_t)(row0 + r) * FO + c] = acc + b[c];
}

extern "C" void kernel_launch(void* const* d_in, const int* in_sizes, int n_in,
                              void* d_out, int out_size, void* d_ws, size_t ws_size,
                              hipStream_t stream) {
  const float* x   = (const float*)d_in[0];
  const int*   ei  = (const int*)d_in[1];
  const float* Wn0 = (const float*)d_in[2];
  const float* b0  = (const float*)d_in[3];
  const float* Ws0 = (const float*)d_in[4];
  const float* Wn1 = (const float*)d_in[5];
  const float* b1  = (const float*)d_in[6];
  const float* Ws1 = (const float*)d_in[7];
  const float* Wn2 = (const float*)d_in[8];
  const float* b2  = (const float*)d_in[9];
  const float* Ws2 = (const float*)d_in[10];
  const float* g0  = (const float*)d_in[11];
  const float* be0 = (const float*)d_in[12];
  const float* rm0 = (const float*)d_in[13];
  const float* rv0 = (const float*)d_in[14];
  const float* g1  = (const float*)d_in[15];
  const float* be1 = (const float*)d_in[16];
  const float* rm1 = (const float*)d_in[17];
  const float* rv1 = (const float*)d_in[18];

  const int* src = ei;       // edge_index[0]
  const int* dst = ei + E;   // edge_index[1]

  // ws layout: degc[N] ints | slots[N*CAP] ints | agg[N*F] f32 | h[N*F] f32
  // = 0.4 MB + 25.6 MB + 51.2 MB + 51.2 MB = 128.4 MB
  int* degc   = (int*)d_ws;
  int* slots  = degc + N;
  float* agg  = (float*)(slots + (size_t)N * CAP);
  float* h    = agg + (size_t)N * F;

  // ---- build adjacency (once; shared by all 3 layers) ----
  hipMemsetAsync(degc, 0, N * sizeof(int), stream);
  fill_k<<<2048, 256, 0, stream>>>(src, dst, degc, slots);

  // ---- layer 0 ----
  agg_k<<<N / 2, 256, 0, stream>>>(degc, slots, x, agg);
  fused_hidden_k<<<N / 32, 256, 0, stream>>>(agg, x, Wn0, b0, Ws0,
                                             g0, be0, rm0, rv0, h);

  // ---- layer 1 (in-place on h) ----
  agg_k<<<N / 2, 256, 0, stream>>>(degc, slots, h, agg);
  fused_hidden_k<<<N / 32, 256, 0, stream>>>(agg, h, Wn1, b1, Ws1,
                                             g1, be1, rm1, rv1, h);

  // ---- layer 2 (output) ----
  agg_k<<<N / 2, 256, 0, stream>>>(degc, slots, h, agg);
  out_k<<<N / 16, 256, 0, stream>>>(agg, h, Wn2, b2, Ws2, (float*)d_out);
}

// Round 8
// 693.030 us; speedup vs baseline: 12.4985x; 1.3665x over previous
//
#include <hip/hip_runtime.h>
#include <hip/hip_bf16.h>

// GraphSAGE 3-layer, N=100000, E=1600000, 128->128->16, f32.
// R3 (5th resubmit; five GPU-acquisition timeouts, kernel never ran):
//   algebraic restructure: agg(h)@Wn == agg(h@Wn).
//   per layer: dual_gemm (y=h@Wn [bf16], s=h@Ws+b [f32])  -> agg_epi (gather-mean
//   y in bf16 + BN + ReLU fused). Layer 2 aggregates 16-wide y2 (8x less gather).

constexpr int N   = 100000;
constexpr int E   = 1600000;
constexpr int F   = 128;
constexpr int FO  = 16;
constexpr int CAP = 64;   // max in-degree; Poisson(16)

__device__ __forceinline__ float bf_lo(unsigned u) {
  return __uint_as_float(u << 16);
}
__device__ __forceinline__ float bf_hi(unsigned u) {
  return __uint_as_float(u & 0xffff0000u);
}

// ---------------- bucket fill: slots[dst][k] = src, degc[dst] = in-degree ----
__global__ void fill_k(const int* __restrict__ src, const int* __restrict__ dst,
                       int* __restrict__ degc, int* __restrict__ slots) {
  int i = blockIdx.x * blockDim.x + threadIdx.x;
  int stride = gridDim.x * blockDim.x;
  for (; i < E; i += stride) {
    int d = dst[i];
    int pos = atomicAdd(&degc[d], 1);
    if (pos < CAP) slots[(size_t)d * CAP + pos] = src[i];
  }
}

// ------------- dual GEMM: y = h@Wn (bf16), s = h@Ws + b (f32) ----------------
// block 256 = 64 rows; thread = (c2 in [0,64), rq in [0,4)): 16 rows x 2 cols.
// LDS reads are wave-uniform broadcasts (all lanes same addr) -> conflict-free.
__global__ __launch_bounds__(256) void dual_gemm_k(
    const float* __restrict__ h_in,
    const float* __restrict__ Wn, const float* __restrict__ Ws,
    const float* __restrict__ b,
    ushort* __restrict__ y, float* __restrict__ s) {
  __shared__ float hL[64][F];
  const int tid = threadIdx.x;
  const int row0 = blockIdx.x * 64;

#pragma unroll
  for (int j = 0; j < 8; ++j) {
    int f = tid + j * 256;           // float4 index in 64x32 tile
    int r = f >> 5;
    int gr = row0 + r; if (gr >= N) gr = N - 1;   // clamp (tail block)
    int cc = f & 31;
    reinterpret_cast<float4*>(&hL[r][0])[cc] =
        reinterpret_cast<const float4*>(h_in + (size_t)gr * F)[cc];
  }
  __syncthreads();

  const int c2 = tid & 63;
  const int rq = tid >> 6;
  float accy0[16], accy1[16], accs0[16], accs1[16];
#pragma unroll
  for (int r = 0; r < 16; ++r) { accy0[r] = 0.f; accy1[r] = 0.f; accs0[r] = 0.f; accs1[r] = 0.f; }

  for (int k0 = 0; k0 < F; k0 += 4) {
    float wn0a = Wn[(k0 + 0) * F + c2], wn0b = Wn[(k0 + 0) * F + c2 + 64];
    float wn1a = Wn[(k0 + 1) * F + c2], wn1b = Wn[(k0 + 1) * F + c2 + 64];
    float wn2a = Wn[(k0 + 2) * F + c2], wn2b = Wn[(k0 + 2) * F + c2 + 64];
    float wn3a = Wn[(k0 + 3) * F + c2], wn3b = Wn[(k0 + 3) * F + c2 + 64];
    float ws0a = Ws[(k0 + 0) * F + c2], ws0b = Ws[(k0 + 0) * F + c2 + 64];
    float ws1a = Ws[(k0 + 1) * F + c2], ws1b = Ws[(k0 + 1) * F + c2 + 64];
    float ws2a = Ws[(k0 + 2) * F + c2], ws2b = Ws[(k0 + 2) * F + c2 + 64];
    float ws3a = Ws[(k0 + 3) * F + c2], ws3b = Ws[(k0 + 3) * F + c2 + 64];
#pragma unroll
    for (int r = 0; r < 16; ++r) {
      float4 hv = *reinterpret_cast<const float4*>(&hL[rq * 16 + r][k0]);
      accy0[r] += hv.x * wn0a + hv.y * wn1a + hv.z * wn2a + hv.w * wn3a;
      accy1[r] += hv.x * wn0b + hv.y * wn1b + hv.z * wn2b + hv.w * wn3b;
      accs0[r] += hv.x * ws0a + hv.y * ws1a + hv.z * ws2a + hv.w * ws3a;
      accs1[r] += hv.x * ws0b + hv.y * ws1b + hv.z * ws2b + hv.w * ws3b;
    }
  }

  const float bc0 = b[c2], bc1 = b[c2 + 64];
#pragma unroll
  for (int r = 0; r < 16; ++r) {
    int gr = row0 + rq * 16 + r;
    if (gr < N) {
      y[(size_t)gr * F + c2]      = __bfloat16_as_ushort(__float2bfloat16(accy0[r]));
      y[(size_t)gr * F + c2 + 64] = __bfloat16_as_ushort(__float2bfloat16(accy1[r]));
      s[(size_t)gr * F + c2]      = accs0[r] + bc0;
      s[(size_t)gr * F + c2 + 64] = accs1[r] + bc1;
    }
  }
}

// ------- agg + epilogue: h_out = relu(bn( mean_gather(y) + s )) --------------
// block 256 = 4 nodes x 64 threads; thread owns channel pair (2*c2, 2*c2+1)
__global__ __launch_bounds__(256) void agg_epi_k(
    const int* __restrict__ degc, const int* __restrict__ slots,
    const ushort* __restrict__ y, const float* __restrict__ s,
    const float* __restrict__ g, const float* __restrict__ be,
    const float* __restrict__ rm, const float* __restrict__ rv,
    float* __restrict__ h_out) {
  const int node = blockIdx.x * 4 + (threadIdx.x >> 6);
  const int c2 = threadIdx.x & 63;
  int deg = degc[node]; if (deg > CAP) deg = CAP;
  const int* sl = slots + (size_t)node * CAP;

  float a0 = 0.f, a1 = 0.f, a2 = 0.f, a3 = 0.f;   // channel lo, 4 streams
  float b0 = 0.f, b1 = 0.f, b2 = 0.f, b3 = 0.f;   // channel hi
  int e = 0;
  for (; e + 4 <= deg; e += 4) {
    int n0 = sl[e], n1 = sl[e + 1], n2 = sl[e + 2], n3 = sl[e + 3];
    unsigned u0 = *reinterpret_cast<const unsigned*>(y + (size_t)n0 * F + c2 * 2);
    unsigned u1 = *reinterpret_cast<const unsigned*>(y + (size_t)n1 * F + c2 * 2);
    unsigned u2 = *reinterpret_cast<const unsigned*>(y + (size_t)n2 * F + c2 * 2);
    unsigned u3 = *reinterpret_cast<const unsigned*>(y + (size_t)n3 * F + c2 * 2);
    a0 += bf_lo(u0); b0 += bf_hi(u0);
    a1 += bf_lo(u1); b1 += bf_hi(u1);
    a2 += bf_lo(u2); b2 += bf_hi(u2);
    a3 += bf_lo(u3); b3 += bf_hi(u3);
  }
  for (; e < deg; ++e) {
    unsigned u = *reinterpret_cast<const unsigned*>(y + (size_t)sl[e] * F + c2 * 2);
    a0 += bf_lo(u); b0 += bf_hi(u);
  }
  const float inv = 1.0f / fmaxf((float)deg, 1.0f);
  const float mlo = ((a0 + a1) + (a2 + a3)) * inv;
  const float mhi = ((b0 + b1) + (b2 + b3)) * inv;

  const int cA = 2 * c2;
  float2 sv = *reinterpret_cast<const float2*>(s + (size_t)node * F + cA);
  float2 gv = *reinterpret_cast<const float2*>(g + cA);
  float2 bev = *reinterpret_cast<const float2*>(be + cA);
  float2 rmv = *reinterpret_cast<const float2*>(rm + cA);
  float2 rvv = *reinterpret_cast<const float2*>(rv + cA);
  float olo = (mlo + sv.x - rmv.x) * (rsqrtf(rvv.x + 1e-5f) * gv.x) + bev.x;
  float ohi = (mhi + sv.y - rmv.y) * (rsqrtf(rvv.y + 1e-5f) * gv.y) + bev.y;
  float2 o = make_float2(fmaxf(olo, 0.f), fmaxf(ohi, 0.f));
  *reinterpret_cast<float2*>(h_out + (size_t)node * F + cA) = o;
}

// ------------- layer-2 dual GEMM 128->16: y2 = h@Wn2 (bf16), s2 = h@Ws2+b2 ---
// block 256 = 16 rows x 16 cols, one output pair per thread
__global__ __launch_bounds__(256) void gemm2_k(
    const float* __restrict__ h_in,
    const float* __restrict__ Wn, const float* __restrict__ Ws,
    const float* __restrict__ b,
    ushort* __restrict__ y2, float* __restrict__ s2) {
  __shared__ float hL[16][F];
  const int tid = threadIdx.x;
  const int row0 = blockIdx.x * 16;
#pragma unroll
  for (int j = 0; j < 2; ++j) {
    int f = tid + j * 256;
    int r = f >> 5;
    int cc = f & 31;
    reinterpret_cast<float4*>(&hL[r][0])[cc] =
        reinterpret_cast<const float4*>(h_in + (size_t)(row0 + r) * F)[cc];
  }
  __syncthreads();

  const int c = tid & 15;
  const int r = tid >> 4;
  float ay = 0.f, as = 0.f;
  for (int k0 = 0; k0 < F; k0 += 4) {
    float4 hv = *reinterpret_cast<const float4*>(&hL[r][k0]);
    ay += hv.x * Wn[(k0 + 0) * FO + c] + hv.y * Wn[(k0 + 1) * FO + c]
        + hv.z * Wn[(k0 + 2) * FO + c] + hv.w * Wn[(k0 + 3) * FO + c];
    as += hv.x * Ws[(k0 + 0) * FO + c] + hv.y * Ws[(k0 + 1) * FO + c]
        + hv.z * Ws[(k0 + 2) * FO + c] + hv.w * Ws[(k0 + 3) * FO + c];
  }
  y2[(size_t)(row0 + r) * FO + c] = __bfloat16_as_ushort(__float2bfloat16(ay));
  s2[(size_t)(row0 + r) * FO + c] = as + b[c];
}

// ------------- output agg: out = mean_gather(y2) + s2 ------------------------
// block 256 = 4 nodes (1 wave each); lane: c = lane&15, j = lane>>4 edge stripe
__global__ __launch_bounds__(256) void agg_out_k(
    const int* __restrict__ degc, const int* __restrict__ slots,
    const ushort* __restrict__ y2, const float* __restrict__ s2,
    float* __restrict__ out) {
  const int node = blockIdx.x * 4 + (threadIdx.x >> 6);
  const int lane = threadIdx.x & 63;
  const int c = lane & 15;
  const int j = lane >> 4;
  int deg = degc[node]; if (deg > CAP) deg = CAP;
  const int* sl = slots + (size_t)node * CAP;
  float acc = 0.f;
  for (int e = j; e < deg; e += 4) {
    unsigned bits = y2[(size_t)sl[e] * FO + c];
    acc += __uint_as_float(bits << 16);
  }
  acc += __shfl_xor(acc, 16, 64);
  acc += __shfl_xor(acc, 32, 64);
  if (j == 0)
    out[(size_t)node * FO + c] = acc / fmaxf((float)deg, 1.0f) + s2[(size_t)node * FO + c];
}

extern "C" void kernel_launch(void* const* d_in, const int* in_sizes, int n_in,
                              void* d_out, int out_size, void* d_ws, size_t ws_size,
                              hipStream_t stream) {
  const float* x   = (const float*)d_in[0];
  const int*   ei  = (const int*)d_in[1];
  const float* Wn0 = (const float*)d_in[2];
  const float* b0  = (const float*)d_in[3];
  const float* Ws0 = (const float*)d_in[4];
  const float* Wn1 = (const float*)d_in[5];
  const float* b1  = (const float*)d_in[6];
  const float* Ws1 = (const float*)d_in[7];
  const float* Wn2 = (const float*)d_in[8];
  const float* b2  = (const float*)d_in[9];
  const float* Ws2 = (const float*)d_in[10];
  const float* g0  = (const float*)d_in[11];
  const float* be0 = (const float*)d_in[12];
  const float* rm0 = (const float*)d_in[13];
  const float* rv0 = (const float*)d_in[14];
  const float* g1  = (const float*)d_in[15];
  const float* be1 = (const float*)d_in[16];
  const float* rm1 = (const float*)d_in[17];
  const float* rv1 = (const float*)d_in[18];

  const int* src = ei;       // edge_index[0]
  const int* dst = ei + E;   // edge_index[1]

  // ws layout: degc[N] int | slots[N*CAP] int | y[N*F] bf16 | s[N*F] f32 | h[N*F] f32
  // = 0.4 + 25.6 + 25.6 + 51.2 + 51.2 = 154 MB  (same footprint as proven R1)
  int* degc    = (int*)d_ws;
  int* slots   = degc + N;
  ushort* y    = (ushort*)(slots + (size_t)N * CAP);
  float* s     = (float*)(y + (size_t)N * F);
  float* h     = s + (size_t)N * F;
  ushort* y2   = y;             // layer-2 reuse (N*FO bf16 fits in y)
  float* s2    = s;             // layer-2 reuse (N*FO f32 fits in s)

  // ---- build adjacency once ----
  hipMemsetAsync(degc, 0, N * sizeof(int), stream);
  fill_k<<<2048, 256, 0, stream>>>(src, dst, degc, slots);

  const int gemm_grid = (N + 63) / 64;   // 1563

  // ---- layer 0 ----
  dual_gemm_k<<<gemm_grid, 256, 0, stream>>>(x, Wn0, Ws0, b0, y, s);
  agg_epi_k<<<N / 4, 256, 0, stream>>>(degc, slots, y, s, g0, be0, rm0, rv0, h);

  // ---- layer 1 ----
  dual_gemm_k<<<gemm_grid, 256, 0, stream>>>(h, Wn1, Ws1, b1, y, s);
  agg_epi_k<<<N / 4, 256, 0, stream>>>(degc, slots, y, s, g1, be1, rm1, rv1, h);

  // ---- layer 2 (output) ----
  gemm2_k<<<N / 16, 256, 0, stream>>>(h, Wn2, Ws2, b2, y2, s2);
  agg_out_k<<<N / 4, 256, 0, stream>>>(degc, slots, y2, s2, (float*)d_out);
}

// Round 9
// 539.324 us; speedup vs baseline: 16.0605x; 1.2850x over previous
//
#include <hip/hip_runtime.h>
#include <hip/hip_bf16.h>

// GraphSAGE 3-layer, N=100000, E=1600000, 128->128->16, f32.
// R9: dual_gemm (44.6 TF f32-vector, 2x147us = 42% of total) -> MFMA bf16.
//   y|s = h @ [Wn|Ws] via mfma_f32_16x16x32_bf16, split-bf16 A (h = hi+lo,
//   2 MFMAs) so only weight bf16-rounding adds error. Weights prepacked
//   transposed bf16 Bt[256][128]. LDS A-tiles XOR-swizzled (guide 6-G4).
// Aggregation path (fill/agg_epi/gemm2/agg_out) unchanged from measured R8.

constexpr int N   = 100000;
constexpr int E   = 1600000;
constexpr int F   = 128;
constexpr int FO  = 16;
constexpr int CAP = 64;   // max in-degree; Poisson(16)

typedef __attribute__((ext_vector_type(8))) short bf16x8;
typedef __attribute__((ext_vector_type(4))) float f32x4;

__device__ __forceinline__ ushort f2bf(float v) {
  return __bfloat16_as_ushort(__float2bfloat16(v));
}
__device__ __forceinline__ float bf2f(ushort u) {
  return __uint_as_float(((unsigned)u) << 16);
}
__device__ __forceinline__ float bf_lo(unsigned u) {
  return __uint_as_float(u << 16);
}
__device__ __forceinline__ float bf_hi(unsigned u) {
  return __uint_as_float(u & 0xffff0000u);
}

// ---------------- bucket fill: slots[dst][k] = src, degc[dst] = in-degree ----
__global__ void fill_k(const int* __restrict__ src, const int* __restrict__ dst,
                       int* __restrict__ degc, int* __restrict__ slots) {
  int i = blockIdx.x * blockDim.x + threadIdx.x;
  int stride = gridDim.x * blockDim.x;
  for (; i < E; i += stride) {
    int d = dst[i];
    int pos = atomicAdd(&degc[d], 1);
    if (pos < CAP) slots[(size_t)d * CAP + pos] = src[i];
  }
}

// ------------- weight prepack: Bt[n][k] = bf16( [Wn|Ws][k][n] ), n<256,k<128 --
__global__ void pack_bt_k(const float* __restrict__ Wn, const float* __restrict__ Ws,
                          ushort* __restrict__ Bt) {
  int t = blockIdx.x * blockDim.x + threadIdx.x;   // 32768 threads
  int n = t >> 7;
  int k = t & 127;
  float w = (n < 128) ? Wn[k * F + n] : Ws[k * F + (n - 128)];
  Bt[t] = f2bf(w);   // Bt[n*128 + k]
}

// ------------- MFMA dual GEMM: [y|s](64 x 256) = h(64 x 128) @ Bt^T ----------
// block 256 = 4 waves; wave w owns cols [w*64, w*64+64). Waves 0,1 -> y (bf16),
// waves 2,3 -> s (f32 + bias). Split-bf16 A: h = Ahi + Alo, 2 MFMAs each.
__global__ __launch_bounds__(256) void dual_gemm_mfma_k(
    const float* __restrict__ h_in, const ushort* __restrict__ Bt,
    const float* __restrict__ b,
    ushort* __restrict__ y, float* __restrict__ s) {
  __shared__ uint4 AsU[2048];              // 32 KB: Ahi[64][256B] then Alo
  char* Ahi = reinterpret_cast<char*>(AsU);
  char* Alo = Ahi + 64 * 256;
  const int tid = threadIdx.x;
  const int row0 = blockIdx.x * 64;

  // ---- stage A as bf16 hi/lo with XOR swizzle (rows are 256B: 16-way conflict
  //      unswizzled; ^((row&7)<<4) spreads 8 rows over all banks) ----
#pragma unroll
  for (int j = 0; j < 4; ++j) {
    int f = tid + j * 256;                 // 16B-chunk index, 1024 total
    int row = f >> 4;
    int kc = f & 15;                       // chunk of 8 k-elements
    int gr = row0 + row; if (gr >= N) gr = N - 1;
    const float4* gp = reinterpret_cast<const float4*>(h_in + (size_t)gr * F + kc * 8);
    float4 v0 = gp[0], v1 = gp[1];
    float vv[8] = {v0.x, v0.y, v0.z, v0.w, v1.x, v1.y, v1.z, v1.w};
    unsigned ph[4], pl[4];
#pragma unroll
    for (int q = 0; q < 4; ++q) {
      ushort h0 = f2bf(vv[2 * q]);
      ushort h1 = f2bf(vv[2 * q + 1]);
      ushort l0 = f2bf(vv[2 * q] - bf2f(h0));
      ushort l1 = f2bf(vv[2 * q + 1] - bf2f(h1));
      ph[q] = (unsigned)h0 | ((unsigned)h1 << 16);
      pl[q] = (unsigned)l0 | ((unsigned)l1 << 16);
    }
    int off = (row * 256 + kc * 16) ^ ((row & 7) << 4);
    *reinterpret_cast<uint4*>(Ahi + off) = make_uint4(ph[0], ph[1], ph[2], ph[3]);
    *reinterpret_cast<uint4*>(Alo + off) = make_uint4(pl[0], pl[1], pl[2], pl[3]);
  }
  __syncthreads();

  const int lane = tid & 63;
  const int wave = tid >> 6;
  const int wcol0 = wave * 64;
  const int lg = lane >> 4;                // quad group 0..3 (k-subrange)
  const int lr = lane & 15;                // row/col within fragment

  f32x4 acc[4][4];
#pragma unroll
  for (int r = 0; r < 4; ++r)
#pragma unroll
    for (int c = 0; c < 4; ++c) acc[r][c] = f32x4{0.f, 0.f, 0.f, 0.f};

#pragma unroll
  for (int kk = 0; kk < 4; ++kk) {         // K-steps of 32
    bf16x8 bfr[4];
#pragma unroll
    for (int c = 0; c < 4; ++c) {
      int col = wcol0 + c * 16 + lr;
      // B-frag: Bt[col][kk*32 + lg*8 .. +8] -- 16B contiguous, L1/L2-resident
      bfr[c] = *reinterpret_cast<const bf16x8*>(Bt + (size_t)col * F + kk * 32 + lg * 8);
    }
#pragma unroll
    for (int r = 0; r < 4; ++r) {          // hi part
      int row = r * 16 + lr;
      int off = (row * 256 + kk * 64 + lg * 16) ^ ((row & 7) << 4);
      bf16x8 a = *reinterpret_cast<const bf16x8*>(Ahi + off);
#pragma unroll
      for (int c = 0; c < 4; ++c)
        acc[r][c] = __builtin_amdgcn_mfma_f32_16x16x32_bf16(a, bfr[c], acc[r][c], 0, 0, 0);
    }
#pragma unroll
    for (int r = 0; r < 4; ++r) {          // lo part (residual)
      int row = r * 16 + lr;
      int off = (row * 256 + kk * 64 + lg * 16) ^ ((row & 7) << 4);
      bf16x8 a = *reinterpret_cast<const bf16x8*>(Alo + off);
#pragma unroll
      for (int c = 0; c < 4; ++c)
        acc[r][c] = __builtin_amdgcn_mfma_f32_16x16x32_bf16(a, bfr[c], acc[r][c], 0, 0, 0);
    }
  }

  // ---- epilogue: C layout col=lane&15, row=(lane>>4)*4+reg (verified m89) ----
  if (wave < 2) {
#pragma unroll
    for (int r = 0; r < 4; ++r)
#pragma unroll
      for (int c = 0; c < 4; ++c) {
        int col = wcol0 + c * 16 + lr;
#pragma unroll
        for (int q = 0; q < 4; ++q) {
          int grow = row0 + r * 16 + lg * 4 + q;
          if (grow < N) y[(size_t)grow * F + col] = f2bf(acc[r][c][q]);
        }
      }
  } else {
#pragma unroll
    for (int r = 0; r < 4; ++r)
#pragma unroll
      for (int c = 0; c < 4; ++c) {
        int scol = wcol0 - 128 + c * 16 + lr;
        float bias = b[scol];
#pragma unroll
        for (int q = 0; q < 4; ++q) {
          int grow = row0 + r * 16 + lg * 4 + q;
          if (grow < N) s[(size_t)grow * F + scol] = acc[r][c][q] + bias;
        }
      }
  }
}

// ------- agg + epilogue: h_out = relu(bn( mean_gather(y) + s )) --------------
// block 256 = 4 nodes x 64 threads; thread owns channel pair (2*c2, 2*c2+1)
__global__ __launch_bounds__(256) void agg_epi_k(
    const int* __restrict__ degc, const int* __restrict__ slots,
    const ushort* __restrict__ y, const float* __restrict__ s,
    const float* __restrict__ g, const float* __restrict__ be,
    const float* __restrict__ rm, const float* __restrict__ rv,
    float* __restrict__ h_out) {
  const int node = blockIdx.x * 4 + (threadIdx.x >> 6);
  const int c2 = threadIdx.x & 63;
  int deg = degc[node]; if (deg > CAP) deg = CAP;
  const int* sl = slots + (size_t)node * CAP;

  float a0 = 0.f, a1 = 0.f, a2 = 0.f, a3 = 0.f;   // channel lo, 4 streams
  float b0 = 0.f, b1 = 0.f, b2 = 0.f, b3 = 0.f;   // channel hi
  int e = 0;
  for (; e + 4 <= deg; e += 4) {
    int n0 = sl[e], n1 = sl[e + 1], n2 = sl[e + 2], n3 = sl[e + 3];
    unsigned u0 = *reinterpret_cast<const unsigned*>(y + (size_t)n0 * F + c2 * 2);
    unsigned u1 = *reinterpret_cast<const unsigned*>(y + (size_t)n1 * F + c2 * 2);
    unsigned u2 = *reinterpret_cast<const unsigned*>(y + (size_t)n2 * F + c2 * 2);
    unsigned u3 = *reinterpret_cast<const unsigned*>(y + (size_t)n3 * F + c2 * 2);
    a0 += bf_lo(u0); b0 += bf_hi(u0);
    a1 += bf_lo(u1); b1 += bf_hi(u1);
    a2 += bf_lo(u2); b2 += bf_hi(u2);
    a3 += bf_lo(u3); b3 += bf_hi(u3);
  }
  for (; e < deg; ++e) {
    unsigned u = *reinterpret_cast<const unsigned*>(y + (size_t)sl[e] * F + c2 * 2);
    a0 += bf_lo(u); b0 += bf_hi(u);
  }
  const float inv = 1.0f / fmaxf((float)deg, 1.0f);
  const float mlo = ((a0 + a1) + (a2 + a3)) * inv;
  const float mhi = ((b0 + b1) + (b2 + b3)) * inv;

  const int cA = 2 * c2;
  float2 sv = *reinterpret_cast<const float2*>(s + (size_t)node * F + cA);
  float2 gv = *reinterpret_cast<const float2*>(g + cA);
  float2 bev = *reinterpret_cast<const float2*>(be + cA);
  float2 rmv = *reinterpret_cast<const float2*>(rm + cA);
  float2 rvv = *reinterpret_cast<const float2*>(rv + cA);
  float olo = (mlo + sv.x - rmv.x) * (rsqrtf(rvv.x + 1e-5f) * gv.x) + bev.x;
  float ohi = (mhi + sv.y - rmv.y) * (rsqrtf(rvv.y + 1e-5f) * gv.y) + bev.y;
  float2 o = make_float2(fmaxf(olo, 0.f), fmaxf(ohi, 0.f));
  *reinterpret_cast<float2*>(h_out + (size_t)node * F + cA) = o;
}

// ------------- layer-2 dual GEMM 128->16: y2 = h@Wn2 (bf16), s2 = h@Ws2+b2 ---
__global__ __launch_bounds__(256) void gemm2_k(
    const float* __restrict__ h_in,
    const float* __restrict__ Wn, const float* __restrict__ Ws,
    const float* __restrict__ b,
    ushort* __restrict__ y2, float* __restrict__ s2) {
  __shared__ float hL[16][F];
  const int tid = threadIdx.x;
  const int row0 = blockIdx.x * 16;
#pragma unroll
  for (int j = 0; j < 2; ++j) {
    int f = tid + j * 256;
    int r = f >> 5;
    int cc = f & 31;
    reinterpret_cast<float4*>(&hL[r][0])[cc] =
        reinterpret_cast<const float4*>(h_in + (size_t)(row0 + r) * F)[cc];
  }
  __syncthreads();

  const int c = tid & 15;
  const int r = tid >> 4;
  float ay = 0.f, as = 0.f;
  for (int k0 = 0; k0 < F; k0 += 4) {
    float4 hv = *reinterpret_cast<const float4*>(&hL[r][k0]);
    ay += hv.x * Wn[(k0 + 0) * FO + c] + hv.y * Wn[(k0 + 1) * FO + c]
        + hv.z * Wn[(k0 + 2) * FO + c] + hv.w * Wn[(k0 + 3) * FO + c];
    as += hv.x * Ws[(k0 + 0) * FO + c] + hv.y * Ws[(k0 + 1) * FO + c]
        + hv.z * Ws[(k0 + 2) * FO + c] + hv.w * Ws[(k0 + 3) * FO + c];
  }
  y2[(size_t)(row0 + r) * FO + c] = f2bf(ay);
  s2[(size_t)(row0 + r) * FO + c] = as + b[c];
}

// ------------- output agg: out = mean_gather(y2) + s2 ------------------------
__global__ __launch_bounds__(256) void agg_out_k(
    const int* __restrict__ degc, const int* __restrict__ slots,
    const ushort* __restrict__ y2, const float* __restrict__ s2,
    float* __restrict__ out) {
  const int node = blockIdx.x * 4 + (threadIdx.x >> 6);
  const int lane = threadIdx.x & 63;
  const int c = lane & 15;
  const int j = lane >> 4;
  int deg = degc[node]; if (deg > CAP) deg = CAP;
  const int* sl = slots + (size_t)node * CAP;
  float acc = 0.f;
  for (int e = j; e < deg; e += 4) {
    unsigned bits = y2[(size_t)sl[e] * FO + c];
    acc += __uint_as_float(bits << 16);
  }
  acc += __shfl_xor(acc, 16, 64);
  acc += __shfl_xor(acc, 32, 64);
  if (j == 0)
    out[(size_t)node * FO + c] = acc / fmaxf((float)deg, 1.0f) + s2[(size_t)node * FO + c];
}

extern "C" void kernel_launch(void* const* d_in, const int* in_sizes, int n_in,
                              void* d_out, int out_size, void* d_ws, size_t ws_size,
                              hipStream_t stream) {
  const float* x   = (const float*)d_in[0];
  const int*   ei  = (const int*)d_in[1];
  const float* Wn0 = (const float*)d_in[2];
  const float* b0  = (const float*)d_in[3];
  const float* Ws0 = (const float*)d_in[4];
  const float* Wn1 = (const float*)d_in[5];
  const float* b1  = (const float*)d_in[6];
  const float* Ws1 = (const float*)d_in[7];
  const float* Wn2 = (const float*)d_in[8];
  const float* b2  = (const float*)d_in[9];
  const float* Ws2 = (const float*)d_in[10];
  const float* g0  = (const float*)d_in[11];
  const float* be0 = (const float*)d_in[12];
  const float* rm0 = (const float*)d_in[13];
  const float* rv0 = (const float*)d_in[14];
  const float* g1  = (const float*)d_in[15];
  const float* be1 = (const float*)d_in[16];
  const float* rm1 = (const float*)d_in[17];
  const float* rv1 = (const float*)d_in[18];

  const int* src = ei;       // edge_index[0]
  const int* dst = ei + E;   // edge_index[1]

  // ws layout: degc[N] int | slots[N*CAP] int | y[N*F] bf16 | s[N*F] f32
  //          | h[N*F] f32 | Bt0[256*128] bf16 | Bt1[256*128] bf16   (~154.1 MB)
  int* degc    = (int*)d_ws;
  int* slots   = degc + N;
  ushort* y    = (ushort*)(slots + (size_t)N * CAP);
  float* s     = (float*)(y + (size_t)N * F);
  float* h     = s + (size_t)N * F;
  ushort* Bt0  = (ushort*)(h + (size_t)N * F);
  ushort* Bt1  = Bt0 + 256 * 128;
  ushort* y2   = y;             // layer-2 reuse
  float* s2    = s;             // layer-2 reuse

  // ---- build adjacency + prepack weights (once) ----
  hipMemsetAsync(degc, 0, N * sizeof(int), stream);
  fill_k<<<2048, 256, 0, stream>>>(src, dst, degc, slots);
  pack_bt_k<<<128, 256, 0, stream>>>(Wn0, Ws0, Bt0);
  pack_bt_k<<<128, 256, 0, stream>>>(Wn1, Ws1, Bt1);

  const int gemm_grid = (N + 63) / 64;   // 1563

  // ---- layer 0 ----
  dual_gemm_mfma_k<<<gemm_grid, 256, 0, stream>>>(x, Bt0, b0, y, s);
  agg_epi_k<<<N / 4, 256, 0, stream>>>(degc, slots, y, s, g0, be0, rm0, rv0, h);

  // ---- layer 1 ----
  dual_gemm_mfma_k<<<gemm_grid, 256, 0, stream>>>(h, Bt1, b1, y, s);
  agg_epi_k<<<N / 4, 256, 0, stream>>>(degc, slots, y, s, g1, be1, rm1, rv1, h);

  // ---- layer 2 (output) ----
  gemm2_k<<<N / 16, 256, 0, stream>>>(h, Wn2, Ws2, b2, y2, s2);
  agg_out_k<<<N / 4, 256, 0, stream>>>(degc, slots, y2, s2, (float*)d_out);
}

// Round 10
// 510.647 us; speedup vs baseline: 16.9624x; 1.0562x over previous
//
#include <hip/hip_runtime.h>
#include <hip/hip_bf16.h>

// GraphSAGE 3-layer, N=100000, E=1600000, 128->128->16, f32.
// R10: fill_k (86us, scattered-write-bound, VALU 0.6%) is independent of the
//   layer-0 GEMM (~70us, MFMA-bound) -> fuse into one heterogeneous kernel
//   (3 gemm-blocks : 2 fill-blocks interleaved) so fill hides under MFMA.
//   Slot writes use nontemporal stores to skip L2 write-allocate churn.
// GEMM/aggregation paths otherwise identical to measured R9.

constexpr int N   = 100000;
constexpr int E   = 1600000;
constexpr int F   = 128;
constexpr int FO  = 16;
constexpr int CAP = 64;   // max in-degree; Poisson(16)

constexpr int GEMM_BLOCKS = (N + 63) / 64;        // 1563 = 521*3
constexpr int FILL_BLOCKS = 1042;                 // 521*2
constexpr int FUSED_GRID  = GEMM_BLOCKS + FILL_BLOCKS;  // 2605 = 521*5

typedef __attribute__((ext_vector_type(8))) short bf16x8;
typedef __attribute__((ext_vector_type(4))) float f32x4;

__device__ __forceinline__ ushort f2bf(float v) {
  return __bfloat16_as_ushort(__float2bfloat16(v));
}
__device__ __forceinline__ float bf2f(ushort u) {
  return __uint_as_float(((unsigned)u) << 16);
}
__device__ __forceinline__ float bf_lo(unsigned u) {
  return __uint_as_float(u << 16);
}
__device__ __forceinline__ float bf_hi(unsigned u) {
  return __uint_as_float(u & 0xffff0000u);
}

// ------------- weight prepack (both layers in one launch) --------------------
__global__ void pack2_k(const float* __restrict__ Wn0, const float* __restrict__ Ws0,
                        const float* __restrict__ Wn1, const float* __restrict__ Ws1,
                        ushort* __restrict__ Bt0, ushort* __restrict__ Bt1) {
  int t = blockIdx.x * blockDim.x + threadIdx.x;   // 65536 threads
  int which = t >> 15;
  int i = t & 32767;
  int n = i >> 7;
  int k = i & 127;
  const float* Wn = which ? Wn1 : Wn0;
  const float* Ws = which ? Ws1 : Ws0;
  ushort* Bt = which ? Bt1 : Bt0;
  float w = (n < 128) ? Wn[k * F + n] : Ws[k * F + (n - 128)];
  Bt[i] = f2bf(w);
}

// ------------- MFMA dual GEMM body: [y|s](64x256) = h(64x128) @ Bt^T ---------
__device__ __forceinline__ void gemm_body(
    int bg, int tid,
    const float* __restrict__ h_in, const ushort* __restrict__ Bt,
    const float* __restrict__ b,
    ushort* __restrict__ y, float* __restrict__ s,
    char* Ahi, char* Alo) {
  const int row0 = bg * 64;

  // stage A as bf16 hi/lo, XOR-swizzled (256B rows -> ^((row&7)<<4))
#pragma unroll
  for (int j = 0; j < 4; ++j) {
    int f = tid + j * 256;                 // 16B-chunk index, 1024 total
    int row = f >> 4;
    int kc = f & 15;
    int gr = row0 + row; if (gr >= N) gr = N - 1;
    const float4* gp = reinterpret_cast<const float4*>(h_in + (size_t)gr * F + kc * 8);
    float4 v0 = gp[0], v1 = gp[1];
    float vv[8] = {v0.x, v0.y, v0.z, v0.w, v1.x, v1.y, v1.z, v1.w};
    unsigned ph[4], pl[4];
#pragma unroll
    for (int q = 0; q < 4; ++q) {
      ushort h0 = f2bf(vv[2 * q]);
      ushort h1 = f2bf(vv[2 * q + 1]);
      ushort l0 = f2bf(vv[2 * q] - bf2f(h0));
      ushort l1 = f2bf(vv[2 * q + 1] - bf2f(h1));
      ph[q] = (unsigned)h0 | ((unsigned)h1 << 16);
      pl[q] = (unsigned)l0 | ((unsigned)l1 << 16);
    }
    int off = (row * 256 + kc * 16) ^ ((row & 7) << 4);
    *reinterpret_cast<uint4*>(Ahi + off) = make_uint4(ph[0], ph[1], ph[2], ph[3]);
    *reinterpret_cast<uint4*>(Alo + off) = make_uint4(pl[0], pl[1], pl[2], pl[3]);
  }
  __syncthreads();

  const int lane = tid & 63;
  const int wave = tid >> 6;
  const int wcol0 = wave * 64;
  const int lg = lane >> 4;
  const int lr = lane & 15;

  f32x4 acc[4][4];
#pragma unroll
  for (int r = 0; r < 4; ++r)
#pragma unroll
    for (int c = 0; c < 4; ++c) acc[r][c] = f32x4{0.f, 0.f, 0.f, 0.f};

#pragma unroll
  for (int kk = 0; kk < 4; ++kk) {
    bf16x8 bfr[4];
#pragma unroll
    for (int c = 0; c < 4; ++c) {
      int col = wcol0 + c * 16 + lr;
      bfr[c] = *reinterpret_cast<const bf16x8*>(Bt + (size_t)col * F + kk * 32 + lg * 8);
    }
#pragma unroll
    for (int r = 0; r < 4; ++r) {
      int row = r * 16 + lr;
      int off = (row * 256 + kk * 64 + lg * 16) ^ ((row & 7) << 4);
      bf16x8 a = *reinterpret_cast<const bf16x8*>(Ahi + off);
#pragma unroll
      for (int c = 0; c < 4; ++c)
        acc[r][c] = __builtin_amdgcn_mfma_f32_16x16x32_bf16(a, bfr[c], acc[r][c], 0, 0, 0);
    }
#pragma unroll
    for (int r = 0; r < 4; ++r) {
      int row = r * 16 + lr;
      int off = (row * 256 + kk * 64 + lg * 16) ^ ((row & 7) << 4);
      bf16x8 a = *reinterpret_cast<const bf16x8*>(Alo + off);
#pragma unroll
      for (int c = 0; c < 4; ++c)
        acc[r][c] = __builtin_amdgcn_mfma_f32_16x16x32_bf16(a, bfr[c], acc[r][c], 0, 0, 0);
    }
  }

  if (wave < 2) {
#pragma unroll
    for (int r = 0; r < 4; ++r)
#pragma unroll
      for (int c = 0; c < 4; ++c) {
        int col = wcol0 + c * 16 + lr;
#pragma unroll
        for (int q = 0; q < 4; ++q) {
          int grow = row0 + r * 16 + lg * 4 + q;
          if (grow < N) y[(size_t)grow * F + col] = f2bf(acc[r][c][q]);
        }
      }
  } else {
#pragma unroll
    for (int r = 0; r < 4; ++r)
#pragma unroll
      for (int c = 0; c < 4; ++c) {
        int scol = wcol0 - 128 + c * 16 + lr;
        float bias = b[scol];
#pragma unroll
        for (int q = 0; q < 4; ++q) {
          int grow = row0 + r * 16 + lg * 4 + q;
          if (grow < N) s[(size_t)grow * F + scol] = acc[r][c][q] + bias;
        }
      }
  }
}

// ------------- fused: layer-0 dual GEMM + adjacency fill ---------------------
// groups of 5 blocks: 3 gemm + 2 fill (interleaved for co-residency)
__global__ __launch_bounds__(256) void fused0_k(
    const float* __restrict__ x, const ushort* __restrict__ Bt0,
    const float* __restrict__ b0,
    ushort* __restrict__ y, float* __restrict__ s,
    const int* __restrict__ src, const int* __restrict__ dst,
    int* __restrict__ degc, int* __restrict__ slots) {
  __shared__ uint4 AsU[2048];              // 32 KB: Ahi[64][256B] then Alo
  char* Ahi = reinterpret_cast<char*>(AsU);
  char* Alo = Ahi + 64 * 256;
  const int gid = blockIdx.x;
  const int grp = gid / 5, rem = gid % 5;
  const int tid = threadIdx.x;

  if (rem < 3) {
    gemm_body(grp * 3 + rem, tid, x, Bt0, b0, y, s, Ahi, Alo);
  } else {
    const int bf = grp * 2 + (rem - 3);
    int i = bf * 256 + tid;
    const int stride = FILL_BLOCKS * 256;
    for (; i < E; i += stride) {
      int d = dst[i];
      int pos = atomicAdd(&degc[d], 1);
      if (pos < CAP)
        __builtin_nontemporal_store(src[i], &slots[(size_t)d * CAP + pos]);
    }
  }
}

// ------------- layer-1 dual GEMM (standalone) --------------------------------
__global__ __launch_bounds__(256) void dual_gemm_mfma_k(
    const float* __restrict__ h_in, const ushort* __restrict__ Bt,
    const float* __restrict__ b,
    ushort* __restrict__ y, float* __restrict__ s) {
  __shared__ uint4 AsU[2048];
  char* Ahi = reinterpret_cast<char*>(AsU);
  char* Alo = Ahi + 64 * 256;
  gemm_body(blockIdx.x, threadIdx.x, h_in, Bt, b, y, s, Ahi, Alo);
}

// ------- agg + epilogue: h_out = relu(bn( mean_gather(y) + s )) --------------
__global__ __launch_bounds__(256) void agg_epi_k(
    const int* __restrict__ degc, const int* __restrict__ slots,
    const ushort* __restrict__ y, const float* __restrict__ s,
    const float* __restrict__ g, const float* __restrict__ be,
    const float* __restrict__ rm, const float* __restrict__ rv,
    float* __restrict__ h_out) {
  const int node = blockIdx.x * 4 + (threadIdx.x >> 6);
  const int c2 = threadIdx.x & 63;
  int deg = degc[node]; if (deg > CAP) deg = CAP;
  const int* sl = slots + (size_t)node * CAP;

  float a0 = 0.f, a1 = 0.f, a2 = 0.f, a3 = 0.f;
  float b0 = 0.f, b1 = 0.f, b2 = 0.f, b3 = 0.f;
  int e = 0;
  for (; e + 4 <= deg; e += 4) {
    int n0 = sl[e], n1 = sl[e + 1], n2 = sl[e + 2], n3 = sl[e + 3];
    unsigned u0 = *reinterpret_cast<const unsigned*>(y + (size_t)n0 * F + c2 * 2);
    unsigned u1 = *reinterpret_cast<const unsigned*>(y + (size_t)n1 * F + c2 * 2);
    unsigned u2 = *reinterpret_cast<const unsigned*>(y + (size_t)n2 * F + c2 * 2);
    unsigned u3 = *reinterpret_cast<const unsigned*>(y + (size_t)n3 * F + c2 * 2);
    a0 += bf_lo(u0); b0 += bf_hi(u0);
    a1 += bf_lo(u1); b1 += bf_hi(u1);
    a2 += bf_lo(u2); b2 += bf_hi(u2);
    a3 += bf_lo(u3); b3 += bf_hi(u3);
  }
  for (; e < deg; ++e) {
    unsigned u = *reinterpret_cast<const unsigned*>(y + (size_t)sl[e] * F + c2 * 2);
    a0 += bf_lo(u); b0 += bf_hi(u);
  }
  const float inv = 1.0f / fmaxf((float)deg, 1.0f);
  const float mlo = ((a0 + a1) + (a2 + a3)) * inv;
  const float mhi = ((b0 + b1) + (b2 + b3)) * inv;

  const int cA = 2 * c2;
  float2 sv = *reinterpret_cast<const float2*>(s + (size_t)node * F + cA);
  float2 gv = *reinterpret_cast<const float2*>(g + cA);
  float2 bev = *reinterpret_cast<const float2*>(be + cA);
  float2 rmv = *reinterpret_cast<const float2*>(rm + cA);
  float2 rvv = *reinterpret_cast<const float2*>(rv + cA);
  float olo = (mlo + sv.x - rmv.x) * (rsqrtf(rvv.x + 1e-5f) * gv.x) + bev.x;
  float ohi = (mhi + sv.y - rmv.y) * (rsqrtf(rvv.y + 1e-5f) * gv.y) + bev.y;
  float2 o = make_float2(fmaxf(olo, 0.f), fmaxf(ohi, 0.f));
  *reinterpret_cast<float2*>(h_out + (size_t)node * F + cA) = o;
}

// ------------- layer-2 dual GEMM 128->16 -------------------------------------
__global__ __launch_bounds__(256) void gemm2_k(
    const float* __restrict__ h_in,
    const float* __restrict__ Wn, const float* __restrict__ Ws,
    const float* __restrict__ b,
    ushort* __restrict__ y2, float* __restrict__ s2) {
  __shared__ float hL[16][F];
  const int tid = threadIdx.x;
  const int row0 = blockIdx.x * 16;
#pragma unroll
  for (int j = 0; j < 2; ++j) {
    int f = tid + j * 256;
    int r = f >> 5;
    int cc = f & 31;
    reinterpret_cast<float4*>(&hL[r][0])[cc] =
        reinterpret_cast<const float4*>(h_in + (size_t)(row0 + r) * F)[cc];
  }
  __syncthreads();

  const int c = tid & 15;
  const int r = tid >> 4;
  float ay = 0.f, as = 0.f;
  for (int k0 = 0; k0 < F; k0 += 4) {
    float4 hv = *reinterpret_cast<const float4*>(&hL[r][k0]);
    ay += hv.x * Wn[(k0 + 0) * FO + c] + hv.y * Wn[(k0 + 1) * FO + c]
        + hv.z * Wn[(k0 + 2) * FO + c] + hv.w * Wn[(k0 + 3) * FO + c];
    as += hv.x * Ws[(k0 + 0) * FO + c] + hv.y * Ws[(k0 + 1) * FO + c]
        + hv.z * Ws[(k0 + 2) * FO + c] + hv.w * Ws[(k0 + 3) * FO + c];
  }
  y2[(size_t)(row0 + r) * FO + c] = f2bf(ay);
  s2[(size_t)(row0 + r) * FO + c] = as + b[c];
}

// ------------- output agg: out = mean_gather(y2) + s2 ------------------------
__global__ __launch_bounds__(256) void agg_out_k(
    const int* __restrict__ degc, const int* __restrict__ slots,
    const ushort* __restrict__ y2, const float* __restrict__ s2,
    float* __restrict__ out) {
  const int node = blockIdx.x * 4 + (threadIdx.x >> 6);
  const int lane = threadIdx.x & 63;
  const int c = lane & 15;
  const int j = lane >> 4;
  int deg = degc[node]; if (deg > CAP) deg = CAP;
  const int* sl = slots + (size_t)node * CAP;
  float acc = 0.f;
  for (int e = j; e < deg; e += 4) {
    unsigned bits = y2[(size_t)sl[e] * FO + c];
    acc += __uint_as_float(bits << 16);
  }
  acc += __shfl_xor(acc, 16, 64);
  acc += __shfl_xor(acc, 32, 64);
  if (j == 0)
    out[(size_t)node * FO + c] = acc / fmaxf((float)deg, 1.0f) + s2[(size_t)node * FO + c];
}

extern "C" void kernel_launch(void* const* d_in, const int* in_sizes, int n_in,
                              void* d_out, int out_size, void* d_ws, size_t ws_size,
                              hipStream_t stream) {
  const float* x   = (const float*)d_in[0];
  const int*   ei  = (const int*)d_in[1];
  const float* Wn0 = (const float*)d_in[2];
  const float* b0  = (const float*)d_in[3];
  const float* Ws0 = (const float*)d_in[4];
  const float* Wn1 = (const float*)d_in[5];
  const float* b1  = (const float*)d_in[6];
  const float* Ws1 = (const float*)d_in[7];
  const float* Wn2 = (const float*)d_in[8];
  const float* b2  = (const float*)d_in[9];
  const float* Ws2 = (const float*)d_in[10];
  const float* g0  = (const float*)d_in[11];
  const float* be0 = (const float*)d_in[12];
  const float* rm0 = (const float*)d_in[13];
  const float* rv0 = (const float*)d_in[14];
  const float* g1  = (const float*)d_in[15];
  const float* be1 = (const float*)d_in[16];
  const float* rm1 = (const float*)d_in[17];
  const float* rv1 = (const float*)d_in[18];

  const int* src = ei;       // edge_index[0]
  const int* dst = ei + E;   // edge_index[1]

  // ws layout: degc[N] int | slots[N*CAP] int | y[N*F] bf16 | s[N*F] f32
  //          | h[N*F] f32 | Bt0[256*128] bf16 | Bt1[256*128] bf16   (~154.1 MB)
  int* degc    = (int*)d_ws;
  int* slots   = degc + N;
  ushort* y    = (ushort*)(slots + (size_t)N * CAP);
  float* s     = (float*)(y + (size_t)N * F);
  float* h     = s + (size_t)N * F;
  ushort* Bt0  = (ushort*)(h + (size_t)N * F);
  ushort* Bt1  = Bt0 + 256 * 128;
  ushort* y2   = y;             // layer-2 reuse
  float* s2    = s;             // layer-2 reuse

  // ---- prepack weights + zero degree counters ----
  hipMemsetAsync(degc, 0, N * sizeof(int), stream);
  pack2_k<<<256, 256, 0, stream>>>(Wn0, Ws0, Wn1, Ws1, Bt0, Bt1);

  // ---- layer 0 GEMM + adjacency fill (independent -> fused/overlapped) ----
  fused0_k<<<FUSED_GRID, 256, 0, stream>>>(x, Bt0, b0, y, s, src, dst, degc, slots);
  agg_epi_k<<<N / 4, 256, 0, stream>>>(degc, slots, y, s, g0, be0, rm0, rv0, h);

  // ---- layer 1 ----
  dual_gemm_mfma_k<<<GEMM_BLOCKS, 256, 0, stream>>>(h, Bt1, b1, y, s);
  agg_epi_k<<<N / 4, 256, 0, stream>>>(degc, slots, y, s, g1, be1, rm1, rv1, h);

  // ---- layer 2 (output) ----
  gemm2_k<<<N / 16, 256, 0, stream>>>(h, Wn2, Ws2, b2, y2, s2);
  agg_out_k<<<N / 4, 256, 0, stream>>>(degc, slots, y2, s2, (float*)d_out);
}